// Round 3
// baseline (2488.981 us; speedup 1.0000x reference)
//
#include <hip/hip_runtime.h>
#include <hip/hip_bf16.h>
#include <cstdint>
#include <cstddef>

// Problem dims
#define B_    256
#define T_    64
#define H_    512
#define DIN_  2048
#define BT_   (B_ * T_)     // 16384
#define NPRE_ 2560          // [i_r, i_i, i_n, t1, t2] columns
#define NCAT_ 2048          // [h_r, h_i, h_n, q~] columns

typedef __attribute__((ext_vector_type(8))) __bf16 bf16x8;
typedef __attribute__((ext_vector_type(4))) float  f32x4;

__device__ __forceinline__ float bf2f(unsigned short u) {
    union { unsigned int i; float f; } v; v.i = ((unsigned int)u) << 16; return v.f;
}
__device__ __forceinline__ unsigned short f2bf(float f) {
    union { float f; unsigned int i; } v; v.f = f;
    unsigned int x = v.i;
    return (unsigned short)((x + 0x7fffu + ((x >> 16) & 1u)) >> 16);
}

// async global->LDS, 16B per lane. LDS dest must be wave-uniform base + lane*16
// (tid-linear dest satisfies this: readfirstlane(base)+lane*16 == tid*16).
__device__ __forceinline__ void gload_lds16(const unsigned short* g, unsigned short* l) {
    __builtin_amdgcn_global_load_lds(
        (const __attribute__((address_space(1))) void*)g,
        (__attribute__((address_space(3))) void*)l, 16, 0, 0);
}

// ---------------- cast fp32 -> bf16, 4 elems/thread ----------------
__global__ void cast4_kernel(const float* __restrict__ src,
                             unsigned short* __restrict__ dst, int n4) {
    int i = blockIdx.x * blockDim.x + threadIdx.x;
    if (i >= n4) return;
    const float4 v = ((const float4*)src)[i];
    ushort4 o;
    o.x = f2bf(v.x); o.y = f2bf(v.y); o.z = f2bf(v.z); o.w = f2bf(v.w);
    ((ushort4*)dst)[i] = o;
}

// ---------------- Wqk = Wk^T @ Wq (fp32 in, bf16 out) ----------------
// Wqk[j,h] = sum_o Wk[o,j] * Wq[o,h]; output written to Wcat rows 1536..2047
__global__ __launch_bounds__(256)
void wqk_kernel(const float* __restrict__ Wk, const float* __restrict__ Wq,
                unsigned short* __restrict__ Wout) {
    __shared__ float sk[16][17], sq[16][17];
    const int tid = threadIdx.x;
    const int tx = tid & 15, ty = tid >> 4;
    const int j0 = blockIdx.y * 16, h0 = blockIdx.x * 16;
    float acc = 0.f;
    for (int o0 = 0; o0 < 512; o0 += 16) {
        sk[ty][tx] = Wk[(o0 + ty) * 512 + j0 + tx];
        sq[ty][tx] = Wq[(o0 + ty) * 512 + h0 + tx];
        __syncthreads();
        #pragma unroll
        for (int oo = 0; oo < 16; oo++)
            acc = fmaf(sk[oo][ty], sq[oo][tx], acc);
        __syncthreads();
    }
    Wout[(size_t)(j0 + ty) * 512 + h0 + tx] = f2bf(acc);
}

// bqk[j] = sum_o Wk[o,j] * bq[o]
__global__ void bqk_kernel(const float* __restrict__ Wk, const float* __restrict__ bq,
                           float* __restrict__ bout) {
    int j = blockIdx.x * 64 + threadIdx.x;
    float acc = 0.f;
    for (int o = 0; o < 512; o++)
        acc = fmaf(Wk[o * 512 + j], bq[o], acc);
    bout[j] = acc;
}

// WvT[j,h] = Wv[h,j] (fp32 -> bf16)
__global__ __launch_bounds__(256)
void transpose_cast_kernel(const float* __restrict__ Wv, unsigned short* __restrict__ WvT) {
    __shared__ float s[32][33];
    const int tx = threadIdx.x, ty = threadIdx.y; // 32 x 8
    const int h0 = blockIdx.y * 32, j0 = blockIdx.x * 32;
    #pragma unroll
    for (int r = 0; r < 4; r++) {
        int row = ty + r * 8;
        s[row][tx] = Wv[(size_t)(h0 + row) * 512 + j0 + tx];
    }
    __syncthreads();
    #pragma unroll
    for (int r = 0; r < 4; r++) {
        int row = ty + r * 8;
        WvT[(size_t)(j0 + row) * 512 + h0 + tx] = f2bf(s[tx][row]);
    }
}

// ---------------- bf16 GEMM, recurrent step (direct-load, latency-friendly) ----------------
// C[m,n] = sum_k A[m,k] * W[n,k] + bias[n].  64(M) x 128(N) per block, 64 blocks,
// wave tile 32x64 (acc[2][4]).  Direct L2 loads, no barriers -> waves progress
// independently; unroll-2 keeps two iterations of loads in flight.
__global__ __launch_bounds__(256)
void gemm_rec(const unsigned short* __restrict__ A,
              const unsigned short* __restrict__ W,
              const float* __restrict__ bias,
              float* __restrict__ C, int N, int K) {
    const int n0 = blockIdx.x * 128;
    const int m0 = blockIdx.y * 64;
    const int tid = threadIdx.x;
    const int wave = tid >> 6, lane = tid & 63;
    const int wm = (wave >> 1) * 32, wn = (wave & 1) * 64;
    const int row16 = lane & 15;
    const int kq = (lane >> 4) * 8;

    f32x4 acc[2][4];
    #pragma unroll
    for (int i = 0; i < 2; i++)
        #pragma unroll
        for (int j = 0; j < 4; j++) {
            acc[i][j].x = 0.f; acc[i][j].y = 0.f; acc[i][j].z = 0.f; acc[i][j].w = 0.f;
        }

    const unsigned short* a_base = A + (size_t)(m0 + wm + row16) * K + kq;
    const unsigned short* b_base = W + (size_t)(n0 + wn + row16) * K + kq;

    #pragma unroll 2
    for (int k = 0; k < K; k += 32) {
        bf16x8 a[2], b[4];
        #pragma unroll
        for (int i = 0; i < 2; i++)
            a[i] = *(const bf16x8*)(const void*)(a_base + (size_t)i * 16 * K + k);
        #pragma unroll
        for (int j = 0; j < 4; j++)
            b[j] = *(const bf16x8*)(const void*)(b_base + (size_t)j * 16 * K + k);
        #pragma unroll
        for (int i = 0; i < 2; i++)
            #pragma unroll
            for (int j = 0; j < 4; j++)
                acc[i][j] = __builtin_amdgcn_mfma_f32_16x16x32_bf16(a[i], b[j], acc[i][j], 0, 0, 0);
    }

    const int col = lane & 15;
    const int rbase = (lane >> 4) * 4;
    #pragma unroll
    for (int i = 0; i < 2; i++) {
        #pragma unroll
        for (int j = 0; j < 4; j++) {
            const int n = n0 + wn + j * 16 + col;
            const float bb = bias[n];
            #pragma unroll
            for (int r = 0; r < 4; r++) {
                const int m = m0 + wm + i * 16 + rbase + r;
                C[(size_t)m * N + n] = acc[i][j][r] + bb;
            }
        }
    }
}

// ---------------- bf16 GEMM (m97 LDS-staged variant, throughput path) ----------------
// 128x128 tile, BK=32, global_load_lds width=16 into linear [128][32] LDS (8KB each),
// ds_read_b128 fragments, 16 MFMA/wave/K-step, 2 barriers per K-step.
// Used for the big precompute GEMM. A selected per n-tile: n0 < nsplit -> A0 else A1.
__global__ __launch_bounds__(256)
void gemm_lds(const unsigned short* __restrict__ A0,
              const unsigned short* __restrict__ A1, int nsplit,
              const unsigned short* __restrict__ W,
              const float* __restrict__ bias,
              float* __restrict__ C, int N, int K) {
    __shared__ unsigned short sA[128 * 32];   // [128][32] row-major, 64B/row
    __shared__ unsigned short sB[128 * 32];
    const int n0 = blockIdx.x * 128;
    const int m0 = blockIdx.y * 128;
    const unsigned short* A = (n0 < nsplit) ? A0 : A1;
    const int tid = threadIdx.x;
    const int wave = tid >> 6, lane = tid & 63;
    const int wm = (wave >> 1) * 64, wn = (wave & 1) * 64;
    const int row16 = lane & 15;
    const int kq = (lane >> 4) * 8;

    f32x4 acc[4][4];
    #pragma unroll
    for (int i = 0; i < 4; i++)
        #pragma unroll
        for (int j = 0; j < 4; j++) {
            acc[i][j].x = 0.f; acc[i][j].y = 0.f; acc[i][j].z = 0.f; acc[i][j].w = 0.f;
        }

    // staging: thread t, load L in {0,1}: element lin = (L*256 + t)*8
    //   row = 64*L + t/4, col = (t%4)*8  -> LDS dest = lin (tid-linear, 16B/lane)
    const int srow = tid >> 2;
    const int scol = (tid & 3) * 8;
    const unsigned short* gA0 = A + (size_t)(m0 + srow) * K + scol;
    const unsigned short* gA1 = A + (size_t)(m0 + 64 + srow) * K + scol;
    const unsigned short* gB0 = W + (size_t)(n0 + srow) * K + scol;
    const unsigned short* gB1 = W + (size_t)(n0 + 64 + srow) * K + scol;
    unsigned short* dA0 = sA + tid * 8;
    unsigned short* dA1 = sA + 2048 + tid * 8;
    unsigned short* dB0 = sB + tid * 8;
    unsigned short* dB1 = sB + 2048 + tid * 8;

    for (int k = 0; k < K; k += 32) {
        gload_lds16(gA0 + k, dA0);
        gload_lds16(gA1 + k, dA1);
        gload_lds16(gB0 + k, dB0);
        gload_lds16(gB1 + k, dB1);
        __syncthreads();   // compiler drains vmcnt before s_barrier
        bf16x8 a[4], b[4];
        #pragma unroll
        for (int i = 0; i < 4; i++)
            a[i] = *(const bf16x8*)(const void*)(sA + (wm + i * 16 + row16) * 32 + kq);
        #pragma unroll
        for (int j = 0; j < 4; j++)
            b[j] = *(const bf16x8*)(const void*)(sB + (wn + j * 16 + row16) * 32 + kq);
        #pragma unroll
        for (int i = 0; i < 4; i++)
            #pragma unroll
            for (int j = 0; j < 4; j++)
                acc[i][j] = __builtin_amdgcn_mfma_f32_16x16x32_bf16(a[i], b[j], acc[i][j], 0, 0, 0);
        __syncthreads();   // protect LDS before next stage
    }

    const int col = lane & 15;
    const int rbase = (lane >> 4) * 4;
    #pragma unroll
    for (int i = 0; i < 4; i++) {
        #pragma unroll
        for (int j = 0; j < 4; j++) {
            const int n = n0 + wn + j * 16 + col;
            const float bb = bias[n];
            #pragma unroll
            for (int r = 0; r < 4; r++) {
                const int m = m0 + wm + i * 16 + rbase + r;
                C[(size_t)m * N + n] = acc[i][j][r] + bb;
            }
        }
    }
}

// ---------------- fused attention + ctx (Wv) + gates, one block per batch row ----------------
__global__ __launch_bounds__(512)
void attn_gates_kernel(const float* __restrict__ comb,      // [256, 2048] h_r|h_i|h_n|q~
                       const float* __restrict__ Cpre,      // [16384, 2560] i_r|i_i|i_n|t1|t2
                       const unsigned short* __restrict__ WvT, // [512,512] bf16, WvT[j,h]=Wv[h,j]
                       const float* __restrict__ bv,
                       float* __restrict__ hx,               // [256,512] fp32 in/out
                       unsigned short* __restrict__ hxbf,    // [256,512] bf16 out
                       float* __restrict__ out,              // d_out
                       int t) {
    __shared__ __align__(16) float su_r[H_];
    __shared__ __align__(16) float su_i[H_];
    __shared__ float red0[8], red1[8], red2[8], red3[8];
    const int b = blockIdx.x;
    const int h = threadIdx.x;
    const int lane = h & 63, wv = h >> 6;
    const float* combRow = comb + (size_t)b * NCAT_;
    const float* pre = Cpre + (size_t)(b * T_ + t) * NPRE_;

    const float q  = combRow[1536 + h];
    const float t1 = pre[1536 + h];
    const float ir = pre[h];
    const float t2 = pre[2048 + h];
    const float ii = pre[512 + h];

    float pr0 = q * t1, pr1 = q * ir, pi0 = q * t2, pi1 = q * ii;
    #pragma unroll
    for (int off = 32; off > 0; off >>= 1) {
        pr0 += __shfl_down(pr0, off);
        pr1 += __shfl_down(pr1, off);
        pi0 += __shfl_down(pi0, off);
        pi1 += __shfl_down(pi1, off);
    }
    if (lane == 0) { red0[wv] = pr0; red1[wv] = pr1; red2[wv] = pi0; red3[wv] = pi1; }
    __syncthreads();
    float s_r0 = 0.f, s_r1 = 0.f, s_i0 = 0.f, s_i1 = 0.f;
    #pragma unroll
    for (int w = 0; w < 8; w++) {
        s_r0 += red0[w]; s_r1 += red1[w]; s_i0 += red2[w]; s_i1 += red3[w];
    }
    const float scale = 0.04419417382415922f; // 1/sqrt(512)
    const float prob_r0 = 1.f / (1.f + expf((s_r1 - s_r0) * scale));
    const float prob_i0 = 1.f / (1.f + expf((s_i1 - s_i0) * scale));
    const float u_r = prob_r0 * t1 + (1.f - prob_r0) * ir;
    const float u_i = prob_i0 * t2 + (1.f - prob_i0) * ii;
    su_r[h] = u_r; su_i[h] = u_i;
    __syncthreads();

    float cr = 0.f, ci = 0.f;
    for (int j = 0; j < H_; j += 4) {
        const float4 ur4 = *(const float4*)&su_r[j];
        const float4 ui4 = *(const float4*)&su_i[j];
        const float w0 = bf2f(WvT[(size_t)(j + 0) * H_ + h]);
        const float w1 = bf2f(WvT[(size_t)(j + 1) * H_ + h]);
        const float w2 = bf2f(WvT[(size_t)(j + 2) * H_ + h]);
        const float w3 = bf2f(WvT[(size_t)(j + 3) * H_ + h]);
        cr = fmaf(ur4.x, w0, cr); ci = fmaf(ui4.x, w0, ci);
        cr = fmaf(ur4.y, w1, cr); ci = fmaf(ui4.y, w1, ci);
        cr = fmaf(ur4.z, w2, cr); ci = fmaf(ui4.z, w2, ci);
        cr = fmaf(ur4.w, w3, cr); ci = fmaf(ui4.w, w3, ci);
    }
    const float bvh = bv[h];
    const float rg = 1.f / (1.f + expf(-(cr + bvh + combRow[h])));
    const float ig = 1.f / (1.f + expf(-(ci + bvh + combRow[512 + h])));
    const float i_n = pre[1024 + h];
    const float hn  = combRow[1024 + h];
    const float ng  = tanhf(fmaf(rg, hn, i_n));
    const float hxv = hx[(size_t)b * H_ + h];
    const float hy  = ng + ig * (hxv - ng);
    out[(size_t)(b * T_ + t) * H_ + h] = hy;
    hx[(size_t)b * H_ + h] = hy;
    hxbf[(size_t)b * H_ + h] = f2bf(hy);
    if (t == T_ - 1)
        out[(size_t)B_ * T_ * H_ + (size_t)b * H_ + h] = hy;
}

extern "C" void kernel_launch(void* const* d_in, const int* in_sizes, int n_in,
                              void* d_out, int out_size, void* d_ws, size_t ws_size,
                              hipStream_t stream) {
    const float* input_feats = (const float*)d_in[0];
    const float* aux0   = (const float*)d_in[1];
    const float* W_ih   = (const float*)d_in[2];
    const float* b_ih   = (const float*)d_in[3];
    const float* W_fh0  = (const float*)d_in[4];
    const float* b_fh0  = (const float*)d_in[5];
    const float* W_hh   = (const float*)d_in[6];
    const float* b_hh   = (const float*)d_in[7];
    const float* Wq     = (const float*)d_in[8];
    const float* bq     = (const float*)d_in[9];
    const float* Wk     = (const float*)d_in[10];
    // d_in[11] = bk: cancels inside the 2-way softmax, unused.
    const float* Wv     = (const float*)d_in[12];
    const float* bv     = (const float*)d_in[13];
    float* out = (float*)d_out;

    char* ws = (char*)d_ws;
    size_t off = 0;
    auto alloc = [&](size_t bytes) -> void* {
        void* p = ws + off;
        off += (bytes + 255) & ~(size_t)255;
        return p;
    };
    unsigned short* Xbf  = (unsigned short*)alloc((size_t)BT_ * DIN_ * 2);
    unsigned short* Abf  = (unsigned short*)alloc((size_t)BT_ * DIN_ * 2);
    unsigned short* Wpre = (unsigned short*)alloc((size_t)NPRE_ * DIN_ * 2);
    float*          Cpre = (float*)alloc((size_t)BT_ * NPRE_ * 4);
    unsigned short* Wcat = (unsigned short*)alloc((size_t)NCAT_ * H_ * 2);
    unsigned short* WvT  = (unsigned short*)alloc((size_t)H_ * H_ * 2);
    float* bpre = (float*)alloc((size_t)NPRE_ * 4);
    float* bcat = (float*)alloc((size_t)NCAT_ * 4);
    float* comb = (float*)alloc((size_t)B_ * NCAT_ * 4);
    float* hx   = (float*)alloc((size_t)B_ * H_ * 4);
    unsigned short* hxbf = (unsigned short*)alloc((size_t)B_ * H_ * 2);

    hipMemsetAsync(hx, 0, (size_t)B_ * H_ * 4, stream);
    hipMemsetAsync(hxbf, 0, (size_t)B_ * H_ * 2, stream);

    auto cast = [&](const float* s, unsigned short* d, size_t n) {
        int n4 = (int)(n / 4);
        cast4_kernel<<<(n4 + 255) / 256, 256, 0, stream>>>(s, d, n4);
    };
    cast(input_feats, Xbf, (size_t)BT_ * DIN_);
    cast(aux0, Abf, (size_t)BT_ * DIN_);
    cast(W_ih, Wpre, (size_t)1536 * DIN_);
    cast(W_fh0, Wpre + (size_t)1536 * DIN_, (size_t)1024 * DIN_);
    cast(W_hh, Wcat, (size_t)1536 * H_);

    hipMemcpyAsync(bpre, b_ih, 1536 * 4, hipMemcpyDeviceToDevice, stream);
    hipMemcpyAsync(bpre + 1536, b_fh0, 1024 * 4, hipMemcpyDeviceToDevice, stream);
    hipMemcpyAsync(bcat, b_hh, 1536 * 4, hipMemcpyDeviceToDevice, stream);

    wqk_kernel<<<dim3(32, 32), 256, 0, stream>>>(Wk, Wq, Wcat + (size_t)1536 * H_);
    bqk_kernel<<<8, 64, 0, stream>>>(Wk, bq, bcat + 1536);
    transpose_cast_kernel<<<dim3(16, 16), dim3(32, 8), 0, stream>>>(Wv, WvT);

    // Precompute: Cpre[b*T+t, :] = [gi(i_r,i_i,i_n) | gf(t1,t2)]
    // LDS-staged variant: big throughput-bound GEMM (172 GFLOP).
    gemm_lds<<<dim3(NPRE_ / 128, BT_ / 128), 256, 0, stream>>>(
        Xbf, Abf, 1536, Wpre, bpre, Cpre, NPRE_, DIN_);

    // Sequential recurrence. Small latency-bound GEMM on the direct-load
    // path: 64x128 tile -> 64 blocks (2x CU coverage vs 128x128), unroll-2
    // keeps two K-iterations of loads in flight.
    for (int t = 0; t < T_; t++) {
        gemm_rec<<<dim3(NCAT_ / 128, B_ / 64), 256, 0, stream>>>(
            hxbf, Wcat, bcat, comb, NCAT_, H_);
        attn_gates_kernel<<<B_, H_, 0, stream>>>(comb, Cpre, WvT, bv, hx, hxbf, out, t);
    }
}

// Round 4
// 1901.742 us; speedup vs baseline: 1.3088x; 1.3088x over previous
//
#include <hip/hip_runtime.h>
#include <hip/hip_bf16.h>
#include <cstdint>
#include <cstddef>

// Problem dims
#define B_    256
#define T_    64
#define H_    512
#define DIN_  2048
#define BT_   (B_ * T_)     // 16384
#define NPRE_ 2560          // [i_r, i_i, i_n, t1, t2] columns
#define NCAT_ 2048          // [h_r, h_i, h_n, q~] columns
#define NV_   2048          // [Vt1|Vir|Vt2|Vii] columns

typedef __attribute__((ext_vector_type(8))) __bf16 bf16x8;
typedef __attribute__((ext_vector_type(4))) float  f32x4;

__device__ __forceinline__ float bf2f(unsigned short u) {
    union { unsigned int i; float f; } v; v.i = ((unsigned int)u) << 16; return v.f;
}
__device__ __forceinline__ unsigned short f2bf(float f) {
    union { float f; unsigned int i; } v; v.f = f;
    unsigned int x = v.i;
    return (unsigned short)((x + 0x7fffu + ((x >> 16) & 1u)) >> 16);
}

// async global->LDS, 16B per lane. LDS dest must be wave-uniform base + lane*16
// (tid-linear dest satisfies this: readfirstlane(base)+lane*16 == tid*16).
__device__ __forceinline__ void gload_lds16(const unsigned short* g, unsigned short* l) {
    __builtin_amdgcn_global_load_lds(
        (const __attribute__((address_space(1))) void*)g,
        (__attribute__((address_space(3))) void*)l, 16, 0, 0);
}

// ---------------- cast fp32 -> bf16, 4 elems/thread ----------------
__global__ void cast4_kernel(const float* __restrict__ src,
                             unsigned short* __restrict__ dst, int n4) {
    int i = blockIdx.x * blockDim.x + threadIdx.x;
    if (i >= n4) return;
    const float4 v = ((const float4*)src)[i];
    ushort4 o;
    o.x = f2bf(v.x); o.y = f2bf(v.y); o.z = f2bf(v.z); o.w = f2bf(v.w);
    ((ushort4*)dst)[i] = o;
}

// ---------------- Wqk = Wk^T @ Wq (fp32 in, bf16 out) ----------------
// Wqk[j,h] = sum_o Wk[o,j] * Wq[o,h]; output written to Wcat rows 1536..2047
__global__ __launch_bounds__(256)
void wqk_kernel(const float* __restrict__ Wk, const float* __restrict__ Wq,
                unsigned short* __restrict__ Wout) {
    __shared__ float sk[16][17], sq[16][17];
    const int tid = threadIdx.x;
    const int tx = tid & 15, ty = tid >> 4;
    const int j0 = blockIdx.y * 16, h0 = blockIdx.x * 16;
    float acc = 0.f;
    for (int o0 = 0; o0 < 512; o0 += 16) {
        sk[ty][tx] = Wk[(o0 + ty) * 512 + j0 + tx];
        sq[ty][tx] = Wq[(o0 + ty) * 512 + h0 + tx];
        __syncthreads();
        #pragma unroll
        for (int oo = 0; oo < 16; oo++)
            acc = fmaf(sk[oo][ty], sq[oo][tx], acc);
        __syncthreads();
    }
    Wout[(size_t)(j0 + ty) * 512 + h0 + tx] = f2bf(acc);
}

// bqk[j] = sum_o Wk[o,j] * bq[o]
__global__ void bqk_kernel(const float* __restrict__ Wk, const float* __restrict__ bq,
                           float* __restrict__ bout) {
    int j = blockIdx.x * 64 + threadIdx.x;
    float acc = 0.f;
    for (int o = 0; o < 512; o++)
        acc = fmaf(Wk[o * 512 + j], bq[o], acc);
    bout[j] = acc;
}

// ---------------- bf16 GEMM, recurrent step (direct-load, latency-friendly) ----------------
// C[m,n] = sum_k A[m,k] * W[n,k] + bias[n].  64(M) x 128(N) per block, 64 blocks,
// wave tile 32x64 (acc[2][4]).  Direct L2 loads, no barriers -> waves progress
// independently; unroll-2 keeps two iterations of loads in flight.
__global__ __launch_bounds__(256)
void gemm_rec(const unsigned short* __restrict__ A,
              const unsigned short* __restrict__ W,
              const float* __restrict__ bias,
              float* __restrict__ C, int N, int K) {
    const int n0 = blockIdx.x * 128;
    const int m0 = blockIdx.y * 64;
    const int tid = threadIdx.x;
    const int wave = tid >> 6, lane = tid & 63;
    const int wm = (wave >> 1) * 32, wn = (wave & 1) * 64;
    const int row16 = lane & 15;
    const int kq = (lane >> 4) * 8;

    f32x4 acc[2][4];
    #pragma unroll
    for (int i = 0; i < 2; i++)
        #pragma unroll
        for (int j = 0; j < 4; j++) {
            acc[i][j].x = 0.f; acc[i][j].y = 0.f; acc[i][j].z = 0.f; acc[i][j].w = 0.f;
        }

    const unsigned short* a_base = A + (size_t)(m0 + wm + row16) * K + kq;
    const unsigned short* b_base = W + (size_t)(n0 + wn + row16) * K + kq;

    #pragma unroll 2
    for (int k = 0; k < K; k += 32) {
        bf16x8 a[2], b[4];
        #pragma unroll
        for (int i = 0; i < 2; i++)
            a[i] = *(const bf16x8*)(const void*)(a_base + (size_t)i * 16 * K + k);
        #pragma unroll
        for (int j = 0; j < 4; j++)
            b[j] = *(const bf16x8*)(const void*)(b_base + (size_t)j * 16 * K + k);
        #pragma unroll
        for (int i = 0; i < 2; i++)
            #pragma unroll
            for (int j = 0; j < 4; j++)
                acc[i][j] = __builtin_amdgcn_mfma_f32_16x16x32_bf16(a[i], b[j], acc[i][j], 0, 0, 0);
    }

    const int col = lane & 15;
    const int rbase = (lane >> 4) * 4;
    #pragma unroll
    for (int i = 0; i < 2; i++) {
        #pragma unroll
        for (int j = 0; j < 4; j++) {
            const int n = n0 + wn + j * 16 + col;
            const float bb = bias[n];
            #pragma unroll
            for (int r = 0; r < 4; r++) {
                const int m = m0 + wm + i * 16 + rbase + r;
                C[(size_t)m * N + n] = acc[i][j][r] + bb;
            }
        }
    }
}

// ---------------- bf16 GEMM (m97 LDS-staged variant, throughput path) ----------------
// 128x128 tile, BK=32, global_load_lds width=16 into linear [128][32] LDS (8KB each),
// ds_read_b128 fragments, 16 MFMA/wave/K-step, 2 barriers per K-step.
// Used for the big precompute GEMM. A selected per n-tile: n0 < nsplit -> A0 else A1.
// Epilogue also writes a PACKED bf16 mirror Apk[16384][2048] = [t1|ir|t2|ii]
// (Cpre col -> packed col: [1536,2048)->-1536, [0,512)->+512, [2048,2560)->-1024,
//  [512,1024)->+1024; i_n block [1024,1536) skipped) for the V pre-GEMM.
__global__ __launch_bounds__(256)
void gemm_lds(const unsigned short* __restrict__ A0,
              const unsigned short* __restrict__ A1, int nsplit,
              const unsigned short* __restrict__ W,
              const float* __restrict__ bias,
              float* __restrict__ C,
              unsigned short* __restrict__ Apk, int N, int K) {
    __shared__ unsigned short sA[128 * 32];   // [128][32] row-major, 64B/row
    __shared__ unsigned short sB[128 * 32];
    const int n0 = blockIdx.x * 128;
    const int m0 = blockIdx.y * 128;
    const unsigned short* A = (n0 < nsplit) ? A0 : A1;
    const int tid = threadIdx.x;
    const int wave = tid >> 6, lane = tid & 63;
    const int wm = (wave >> 1) * 64, wn = (wave & 1) * 64;
    const int row16 = lane & 15;
    const int kq = (lane >> 4) * 8;

    f32x4 acc[4][4];
    #pragma unroll
    for (int i = 0; i < 4; i++)
        #pragma unroll
        for (int j = 0; j < 4; j++) {
            acc[i][j].x = 0.f; acc[i][j].y = 0.f; acc[i][j].z = 0.f; acc[i][j].w = 0.f;
        }

    // staging: thread t, load L in {0,1}: element lin = (L*256 + t)*8
    //   row = 64*L + t/4, col = (t%4)*8  -> LDS dest = lin (tid-linear, 16B/lane)
    const int srow = tid >> 2;
    const int scol = (tid & 3) * 8;
    const unsigned short* gA0 = A + (size_t)(m0 + srow) * K + scol;
    const unsigned short* gA1 = A + (size_t)(m0 + 64 + srow) * K + scol;
    const unsigned short* gB0 = W + (size_t)(n0 + srow) * K + scol;
    const unsigned short* gB1 = W + (size_t)(n0 + 64 + srow) * K + scol;
    unsigned short* dA0 = sA + tid * 8;
    unsigned short* dA1 = sA + 2048 + tid * 8;
    unsigned short* dB0 = sB + tid * 8;
    unsigned short* dB1 = sB + 2048 + tid * 8;

    for (int k = 0; k < K; k += 32) {
        gload_lds16(gA0 + k, dA0);
        gload_lds16(gA1 + k, dA1);
        gload_lds16(gB0 + k, dB0);
        gload_lds16(gB1 + k, dB1);
        __syncthreads();   // compiler drains vmcnt before s_barrier
        bf16x8 a[4], b[4];
        #pragma unroll
        for (int i = 0; i < 4; i++)
            a[i] = *(const bf16x8*)(const void*)(sA + (wm + i * 16 + row16) * 32 + kq);
        #pragma unroll
        for (int j = 0; j < 4; j++)
            b[j] = *(const bf16x8*)(const void*)(sB + (wn + j * 16 + row16) * 32 + kq);
        #pragma unroll
        for (int i = 0; i < 4; i++)
            #pragma unroll
            for (int j = 0; j < 4; j++)
                acc[i][j] = __builtin_amdgcn_mfma_f32_16x16x32_bf16(a[i], b[j], acc[i][j], 0, 0, 0);
        __syncthreads();   // protect LDS before next stage
    }

    // packed-column base for the Apk mirror (whole 128-col tile maps uniformly)
    int pbase = -1;
    if (n0 >= 1536 && n0 < 2048)      pbase = n0 - 1536;  // t1 -> [0,512)
    else if (n0 < 512)                pbase = n0 + 512;   // i_r -> [512,1024)
    else if (n0 >= 2048)              pbase = n0 - 1024;  // t2 -> [1024,1536)
    else if (n0 >= 512 && n0 < 1024)  pbase = n0 + 1024;  // i_i -> [1536,2048)
    // n0 in [1024,1536) = i_n -> no mirror

    const int col = lane & 15;
    const int rbase = (lane >> 4) * 4;
    #pragma unroll
    for (int i = 0; i < 4; i++) {
        #pragma unroll
        for (int j = 0; j < 4; j++) {
            const int nloc = wn + j * 16 + col;
            const int n = n0 + nloc;
            const float bb = bias[n];
            #pragma unroll
            for (int r = 0; r < 4; r++) {
                const int m = m0 + wm + i * 16 + rbase + r;
                const float val = acc[i][j][r] + bb;
                C[(size_t)m * N + n] = val;
                if (pbase >= 0)
                    Apk[(size_t)m * NV_ + pbase + nloc] = f2bf(val);
            }
        }
    }
}

// ---------------- V pre-GEMM: Vbf[m, g*512+n'] = sum_k Apk[m, g*512+k]*Wv[n',k] + bv[n'] ----------------
// Hoists Wv through the 2-key softmax: ctx_r = p*Vt1 + (1-p)*Vir etc. (p scalar per b,t).
// Same LDS-staged 128x128 template; A col-group = output col-group; bv folded as bias.
__global__ __launch_bounds__(256)
void gemm_v(const unsigned short* __restrict__ Apk,   // [16384][2048] bf16
            const unsigned short* __restrict__ Wvbf,  // [512][512] bf16 (Wv[o,h], k=h)
            const float* __restrict__ bv,
            unsigned short* __restrict__ Vbf) {       // [16384][2048] bf16
    __shared__ unsigned short sA[128 * 32];
    __shared__ unsigned short sB[128 * 32];
    const int n0 = blockIdx.x * 128;     // 0..1920
    const int m0 = blockIdx.y * 128;
    const int aoff = n0 & ~511;          // column-group base in Apk
    const int nb0 = n0 & 511;            // row base in Wvbf
    const int tid = threadIdx.x;
    const int wave = tid >> 6, lane = tid & 63;
    const int wm = (wave >> 1) * 64, wn = (wave & 1) * 64;
    const int row16 = lane & 15;
    const int kq = (lane >> 4) * 8;

    f32x4 acc[4][4];
    #pragma unroll
    for (int i = 0; i < 4; i++)
        #pragma unroll
        for (int j = 0; j < 4; j++) {
            acc[i][j].x = 0.f; acc[i][j].y = 0.f; acc[i][j].z = 0.f; acc[i][j].w = 0.f;
        }

    const int srow = tid >> 2;
    const int scol = (tid & 3) * 8;
    const unsigned short* gA0 = Apk + (size_t)(m0 + srow) * NV_ + aoff + scol;
    const unsigned short* gA1 = Apk + (size_t)(m0 + 64 + srow) * NV_ + aoff + scol;
    const unsigned short* gB0 = Wvbf + (size_t)(nb0 + srow) * 512 + scol;
    const unsigned short* gB1 = Wvbf + (size_t)(nb0 + 64 + srow) * 512 + scol;
    unsigned short* dA0 = sA + tid * 8;
    unsigned short* dA1 = sA + 2048 + tid * 8;
    unsigned short* dB0 = sB + tid * 8;
    unsigned short* dB1 = sB + 2048 + tid * 8;

    for (int k = 0; k < 512; k += 32) {
        gload_lds16(gA0 + k, dA0);
        gload_lds16(gA1 + k, dA1);
        gload_lds16(gB0 + k, dB0);
        gload_lds16(gB1 + k, dB1);
        __syncthreads();
        bf16x8 a[4], b[4];
        #pragma unroll
        for (int i = 0; i < 4; i++)
            a[i] = *(const bf16x8*)(const void*)(sA + (wm + i * 16 + row16) * 32 + kq);
        #pragma unroll
        for (int j = 0; j < 4; j++)
            b[j] = *(const bf16x8*)(const void*)(sB + (wn + j * 16 + row16) * 32 + kq);
        #pragma unroll
        for (int i = 0; i < 4; i++)
            #pragma unroll
            for (int j = 0; j < 4; j++)
                acc[i][j] = __builtin_amdgcn_mfma_f32_16x16x32_bf16(a[i], b[j], acc[i][j], 0, 0, 0);
        __syncthreads();
    }

    const int col = lane & 15;
    const int rbase = (lane >> 4) * 4;
    #pragma unroll
    for (int i = 0; i < 4; i++) {
        #pragma unroll
        for (int j = 0; j < 4; j++) {
            const int nloc = wn + j * 16 + col;
            const float bb = bv[nb0 + nloc];
            #pragma unroll
            for (int r = 0; r < 4; r++) {
                const int m = m0 + wm + i * 16 + rbase + r;
                Vbf[(size_t)m * NV_ + n0 + nloc] = f2bf(acc[i][j][r] + bb);
            }
        }
    }
}

// ---------------- fused attention + gates (no GEMV: V precomputed) ----------------
__global__ __launch_bounds__(512)
void attn_gates2(const float* __restrict__ comb,      // [256, 2048] h_r|h_i|h_n|q~
                 const float* __restrict__ Cpre,      // [16384, 2560] i_r|i_i|i_n|t1|t2
                 const unsigned short* __restrict__ Vbf, // [16384, 2048] Vt1|Vir|Vt2|Vii (+bv)
                 float* __restrict__ hx,              // [256,512] fp32 in/out
                 unsigned short* __restrict__ hxbf,   // [256,512] bf16 out
                 float* __restrict__ out,             // d_out
                 int t) {
    __shared__ float red0[8], red1[8], red2[8], red3[8];
    const int b = blockIdx.x;
    const int h = threadIdx.x;
    const int lane = h & 63, wv = h >> 6;
    const float* combRow = comb + (size_t)b * NCAT_;
    const float* pre = Cpre + (size_t)(b * T_ + t) * NPRE_;
    const unsigned short* vrow = Vbf + (size_t)(b * T_ + t) * NV_;

    const float q  = combRow[1536 + h];
    const float t1 = pre[1536 + h];
    const float ir = pre[h];
    const float t2 = pre[2048 + h];
    const float ii = pre[512 + h];

    float pr0 = q * t1, pr1 = q * ir, pi0 = q * t2, pi1 = q * ii;
    #pragma unroll
    for (int off = 32; off > 0; off >>= 1) {
        pr0 += __shfl_down(pr0, off);
        pr1 += __shfl_down(pr1, off);
        pi0 += __shfl_down(pi0, off);
        pi1 += __shfl_down(pi1, off);
    }
    if (lane == 0) { red0[wv] = pr0; red1[wv] = pr1; red2[wv] = pi0; red3[wv] = pi1; }
    __syncthreads();
    float s_r0 = 0.f, s_r1 = 0.f, s_i0 = 0.f, s_i1 = 0.f;
    #pragma unroll
    for (int w = 0; w < 8; w++) {
        s_r0 += red0[w]; s_r1 += red1[w]; s_i0 += red2[w]; s_i1 += red3[w];
    }
    const float scale = 0.04419417382415922f; // 1/sqrt(512)
    const float prob_r0 = 1.f / (1.f + expf((s_r1 - s_r0) * scale));
    const float prob_i0 = 1.f / (1.f + expf((s_i1 - s_i0) * scale));

    // ctx + bv, via precomputed V (p is scalar: convex combination is exact)
    const float vt1 = bf2f(vrow[h]);
    const float vir = bf2f(vrow[512 + h]);
    const float vt2 = bf2f(vrow[1024 + h]);
    const float vii = bf2f(vrow[1536 + h]);
    const float cr = prob_r0 * vt1 + (1.f - prob_r0) * vir;
    const float ci = prob_i0 * vt2 + (1.f - prob_i0) * vii;

    const float rg = 1.f / (1.f + expf(-(cr + combRow[h])));
    const float ig = 1.f / (1.f + expf(-(ci + combRow[512 + h])));
    const float i_n = pre[1024 + h];
    const float hn  = combRow[1024 + h];
    const float ng  = tanhf(fmaf(rg, hn, i_n));
    const float hxv = hx[(size_t)b * H_ + h];
    const float hy  = ng + ig * (hxv - ng);
    out[(size_t)(b * T_ + t) * H_ + h] = hy;
    hx[(size_t)b * H_ + h] = hy;
    hxbf[(size_t)b * H_ + h] = f2bf(hy);
    if (t == T_ - 1)
        out[(size_t)B_ * T_ * H_ + (size_t)b * H_ + h] = hy;
}

extern "C" void kernel_launch(void* const* d_in, const int* in_sizes, int n_in,
                              void* d_out, int out_size, void* d_ws, size_t ws_size,
                              hipStream_t stream) {
    const float* input_feats = (const float*)d_in[0];
    const float* aux0   = (const float*)d_in[1];
    const float* W_ih   = (const float*)d_in[2];
    const float* b_ih   = (const float*)d_in[3];
    const float* W_fh0  = (const float*)d_in[4];
    const float* b_fh0  = (const float*)d_in[5];
    const float* W_hh   = (const float*)d_in[6];
    const float* b_hh   = (const float*)d_in[7];
    const float* Wq     = (const float*)d_in[8];
    const float* bq     = (const float*)d_in[9];
    const float* Wk     = (const float*)d_in[10];
    // d_in[11] = bk: cancels inside the 2-way softmax, unused.
    const float* Wv     = (const float*)d_in[12];
    const float* bv     = (const float*)d_in[13];
    float* out = (float*)d_out;

    char* ws = (char*)d_ws;
    size_t off = 0;
    auto alloc = [&](size_t bytes) -> void* {
        void* p = ws + off;
        off += (bytes + 255) & ~(size_t)255;
        return p;
    };
    // Xbf is dead after gemm_lds; Vbf (same size, 64 MiB) reuses its region.
    unsigned short* Xbf  = (unsigned short*)alloc((size_t)BT_ * DIN_ * 2);
    unsigned short* Vbf  = Xbf;
    unsigned short* Abf  = (unsigned short*)alloc((size_t)BT_ * DIN_ * 2);
    unsigned short* Wpre = (unsigned short*)alloc((size_t)NPRE_ * DIN_ * 2);
    float*          Cpre = (float*)alloc((size_t)BT_ * NPRE_ * 4);
    unsigned short* Apk  = (unsigned short*)alloc((size_t)BT_ * NV_ * 2);
    unsigned short* Wcat = (unsigned short*)alloc((size_t)NCAT_ * H_ * 2);
    unsigned short* Wvbf = (unsigned short*)alloc((size_t)H_ * H_ * 2);
    float* bpre = (float*)alloc((size_t)NPRE_ * 4);
    float* bcat = (float*)alloc((size_t)NCAT_ * 4);
    float* comb = (float*)alloc((size_t)B_ * NCAT_ * 4);
    float* hx   = (float*)alloc((size_t)B_ * H_ * 4);
    unsigned short* hxbf = (unsigned short*)alloc((size_t)B_ * H_ * 2);

    hipMemsetAsync(hx, 0, (size_t)B_ * H_ * 4, stream);
    hipMemsetAsync(hxbf, 0, (size_t)B_ * H_ * 2, stream);

    auto cast = [&](const float* s, unsigned short* d, size_t n) {
        int n4 = (int)(n / 4);
        cast4_kernel<<<(n4 + 255) / 256, 256, 0, stream>>>(s, d, n4);
    };
    cast(input_feats, Xbf, (size_t)BT_ * DIN_);
    cast(aux0, Abf, (size_t)BT_ * DIN_);
    cast(W_ih, Wpre, (size_t)1536 * DIN_);
    cast(W_fh0, Wpre + (size_t)1536 * DIN_, (size_t)1024 * DIN_);
    cast(W_hh, Wcat, (size_t)1536 * H_);
    cast(Wv, Wvbf, (size_t)H_ * H_);

    hipMemcpyAsync(bpre, b_ih, 1536 * 4, hipMemcpyDeviceToDevice, stream);
    hipMemcpyAsync(bpre + 1536, b_fh0, 1024 * 4, hipMemcpyDeviceToDevice, stream);
    hipMemcpyAsync(bcat, b_hh, 1536 * 4, hipMemcpyDeviceToDevice, stream);

    wqk_kernel<<<dim3(32, 32), 256, 0, stream>>>(Wk, Wq, Wcat + (size_t)1536 * H_);
    bqk_kernel<<<8, 64, 0, stream>>>(Wk, bq, bcat + 1536);

    // Precompute: Cpre[b*T+t, :] = [gi(i_r,i_i,i_n) | gf(t1,t2)] (+ packed bf16 mirror Apk)
    gemm_lds<<<dim3(NPRE_ / 128, BT_ / 128), 256, 0, stream>>>(
        Xbf, Abf, 1536, Wpre, bpre, Cpre, Apk, NPRE_, DIN_);

    // Precompute V = [Wv*t1 | Wv*ir | Wv*t2 | Wv*ii] + bv  (Xbf region reused for Vbf)
    gemm_v<<<dim3(NV_ / 128, BT_ / 128), 256, 0, stream>>>(Apk, Wvbf, bv, Vbf);

    // Sequential recurrence: small latency-bound GEMM + GEMV-free attention/gates.
    for (int t = 0; t < T_; t++) {
        gemm_rec<<<dim3(NCAT_ / 128, B_ / 64), 256, 0, stream>>>(
            hxbf, Wcat, bcat, comb, NCAT_, H_);
        attn_gates2<<<B_, H_, 0, stream>>>(comb, Cpre, Vbf, hx, hxbf, out, t);
    }
}